// Round 1
// baseline (90.558 us; speedup 1.0000x reference)
//
#include <hip/hip_runtime.h>

#define IMG_W 256
#define IMG_H 256
#define GG 4
#define CUT 15.0f

// ---------------- projection: per-splat params into workspace ----------------
// low layout  (stride 12): [cx, cy, A, B, C, rad, pr, pg, pb, pad, pad, pad]
// high layout (stride 24): [cx, cy, A, B, C, rad, pr, pg, pb, pad, pad, pad,
//                           fx0..fx3, fy0..fy3, w0..w3]
// sigma(dx,dy) = A*dx^2 + B*dx*dy + C*dy^2  with A=0.5*q0, B=q1, C=0.5*q2
__global__ __launch_bounds__(256) void project_kernel(
    const float* __restrict__ low_mu,   const float* __restrict__ low_chol,
    const float* __restrict__ low_feat, const float* __restrict__ low_opac,
    const float* __restrict__ high_mu,  const float* __restrict__ high_chol,
    const float* __restrict__ high_feat,const float* __restrict__ high_opac,
    const float* __restrict__ gfreq,    const float* __restrict__ gweight,
    int nl, int nh,
    float* __restrict__ plow, float* __restrict__ phigh)
{
    int i = blockIdx.x * blockDim.x + threadIdx.x;
    if (i >= nl + nh) return;
    bool islow = (i < nl);
    int k = islow ? i : (i - nl);
    const float* mu   = islow ? low_mu   : high_mu;
    const float* chol = islow ? low_chol : high_chol;
    const float* feat = islow ? low_feat : high_feat;
    const float* opac = islow ? low_opac : high_opac;

    float m0 = tanhf(mu[2*k]);
    float m1 = tanhf(mu[2*k+1]);
    float cx = (m0 + 1.0f) * 0.5f * (float)IMG_W;
    float cy = (m1 + 1.0f) * 0.5f * (float)IMG_H;

    float l1 = chol[3*k]     + 0.5f;
    float l2 = chol[3*k + 1];
    float l3 = chol[3*k + 2] + 0.5f;
    float sxx = l1*l1, sxy = l1*l2, syy = l2*l2 + l3*l3;
    float det = sxx*syy - sxy*sxy;
    float inv = 1.0f / det;
    float q0 = syy*inv, q1 = -sxy*inv, q2 = sxx*inv;

    // conservative cull radius from min eigenvalue of [[q0,q1],[q1,q2]]
    float ht = 0.5f*(q0 + q2);
    float hd = 0.5f*(q0 - q2);
    float lam = ht - sqrtf(hd*hd + q1*q1);
    lam = fmaxf(lam, 1e-6f);
    float rad = sqrtf(2.0f * CUT / lam) + 1.0f;

    float op = opac[k];
    float pr = feat[3*k]*op, pg = feat[3*k+1]*op, pb = feat[3*k+2]*op;

    if (islow) {
        float* p = plow + (size_t)k * 12;
        p[0]=cx; p[1]=cy; p[2]=0.5f*q0; p[3]=q1; p[4]=0.5f*q2; p[5]=rad;
        p[6]=pr; p[7]=pg; p[8]=pb; p[9]=0.f; p[10]=0.f; p[11]=0.f;
    } else {
        float* p = phigh + (size_t)k * 24;
        p[0]=cx; p[1]=cy; p[2]=0.5f*q0; p[3]=q1; p[4]=0.5f*q2; p[5]=rad;
        p[6]=pr; p[7]=pg; p[8]=pb; p[9]=0.f; p[10]=0.f; p[11]=0.f;
        #pragma unroll
        for (int g = 0; g < GG; ++g) {
            p[12+g] = gfreq[(k*GG + g)*2];
            p[16+g] = gfreq[(k*GG + g)*2 + 1];
            p[20+g] = gweight[k*GG + g];
        }
    }
}

// ---------------- raster: one block per 16x16 tile, 1 px/thread -------------
__global__ __launch_bounds__(256) void raster_kernel(
    const float* __restrict__ plow, int nl,
    const float* __restrict__ phigh, int nh,
    float* __restrict__ out)
{
    __shared__ int s_cnt;
    __shared__ int s_list[4096];

    const int tid = threadIdx.x;
    const int bx = blockIdx.x & 15, by = blockIdx.x >> 4;
    const float tx0 = bx*16 + 0.5f, ty0 = by*16 + 0.5f;   // first/last pixel centers
    const float tx1 = tx0 + 15.0f,  ty1 = ty0 + 15.0f;
    const int lx = tid & 15, ly = tid >> 4;
    const float px = bx*16 + lx + 0.5f;
    const float py = by*16 + ly + 0.5f;

    float accr = 0.f, accg = 0.f, accb = 0.f;

    // ---------- phase 1: low-frequency (pure Gaussian) ----------
    if (tid == 0) s_cnt = 0;
    __syncthreads();
    for (int i = tid; i < nl; i += 256) {
        const float* p = plow + (size_t)i * 12;
        float cx = p[0], cy = p[1], rad = p[5];
        if (cx + rad >= tx0 && cx - rad <= tx1 &&
            cy + rad >= ty0 && cy - rad <= ty1) {
            int slot = atomicAdd(&s_cnt, 1);
            s_list[slot] = i;
        }
    }
    __syncthreads();
    int cnt = s_cnt;
    for (int j = 0; j < cnt; ++j) {
        int idx = __builtin_amdgcn_readfirstlane(s_list[j]);  // wave-uniform -> s_load params
        const float* p = plow + (size_t)idx * 12;
        float dx = px - p[0], dy = py - p[1];
        float s  = (p[2]*dx + p[3]*dy)*dx + p[4]*dy*dy;
        float e  = __expf(-s);
        accr = fmaf(e, p[6], accr);
        accg = fmaf(e, p[7], accg);
        accb = fmaf(e, p[8], accb);
    }
    __syncthreads();

    // ---------- phase 2: high-frequency (Gabor-modulated) ----------
    if (tid == 0) s_cnt = 0;
    __syncthreads();
    for (int i = tid; i < nh; i += 256) {
        const float* p = phigh + (size_t)i * 24;
        float cx = p[0], cy = p[1], rad = p[5];
        if (cx + rad >= tx0 && cx - rad <= tx1 &&
            cy + rad >= ty0 && cy - rad <= ty1) {
            int slot = atomicAdd(&s_cnt, 1);
            s_list[slot] = i;
        }
    }
    __syncthreads();
    cnt = s_cnt;
    for (int j = 0; j < cnt; ++j) {
        int idx = __builtin_amdgcn_readfirstlane(s_list[j]);
        const float* p = phigh + (size_t)idx * 24;
        float dx = px - p[0], dy = py - p[1];
        float s  = (p[2]*dx + p[3]*dy)*dx + p[4]*dy*dy;
        float e  = __expf(-s);
        float mod = 0.f;
        #pragma unroll
        for (int g = 0; g < GG; ++g) {
            float ph = p[12+g]*dx + p[16+g]*dy;
            mod = fmaf(p[20+g], __cosf(ph), mod);
        }
        float e2 = e * mod;
        accr = fmaf(e2, p[6], accr);
        accg = fmaf(e2, p[7], accg);
        accb = fmaf(e2, p[8], accb);
    }

    // ---------- write clipped planar output (1,3,H,W) ----------
    int x = bx*16 + lx, y = by*16 + ly;
    int pix = y*IMG_W + x;
    out[pix]                 = fminf(fmaxf(accr, 0.f), 1.f);
    out[IMG_H*IMG_W + pix]   = fminf(fmaxf(accg, 0.f), 1.f);
    out[2*IMG_H*IMG_W + pix] = fminf(fmaxf(accb, 0.f), 1.f);
}

extern "C" void kernel_launch(void* const* d_in, const int* in_sizes, int n_in,
                              void* d_out, int out_size, void* d_ws, size_t ws_size,
                              hipStream_t stream)
{
    const float* low_mu    = (const float*)d_in[0];
    const float* high_mu   = (const float*)d_in[1];
    const float* low_chol  = (const float*)d_in[2];
    const float* high_chol = (const float*)d_in[3];
    const float* low_feat  = (const float*)d_in[4];
    const float* high_feat = (const float*)d_in[5];
    const float* low_opac  = (const float*)d_in[6];
    const float* high_opac = (const float*)d_in[7];
    const float* gfreq     = (const float*)d_in[8];
    const float* gweight   = (const float*)d_in[9];

    int nl = in_sizes[0] / 2;
    int nh = in_sizes[1] / 2;

    float* plow  = (float*)d_ws;                  // nl*12 floats
    float* phigh = plow + (size_t)nl * 12;        // nh*24 floats
    float* out   = (float*)d_out;

    int n = nl + nh;
    project_kernel<<<(n + 255) / 256, 256, 0, stream>>>(
        low_mu, low_chol, low_feat, low_opac,
        high_mu, high_chol, high_feat, high_opac,
        gfreq, gweight, nl, nh, plow, phigh);

    raster_kernel<<<256, 256, 0, stream>>>(plow, nl, phigh, nh, out);
}